// Round 7
// baseline (143.664 us; speedup 1.0000x reference)
//
#include <hip/hip_runtime.h>

#define B_DIM 4096
#define L_DIM 4096
#define SEGLEN 256
#define NSEG (L_DIM / SEGLEN)   // 16
#define WARM 512                // max warm-up (segs 0,1 use exact shorter warm)
#define CHUNK 32                // time steps per LDS chunk
#define CF4 (CHUNK / 4)         // 8 float4 per row per chunk
#define LSTRIDE 36              // LDS floats per row: 32 + 4 pad (conflict-free)
#define RPB 128                 // rows per block (2 per lane)

typedef float f4 __attribute__((ext_vector_type(4)));

// ws: float C_acc[4096], float ts_acc[4096], int first_acc[4096]
__global__ __launch_bounds__(256) void init_kernel(float* wsf, int* wsi) {
    int i = blockIdx.x * 256 + threadIdx.x;
    if (i < 2 * B_DIM) wsf[i] = 0.f;
    if (i < B_DIM) wsi[i] = L_DIM;
}

// Exact IEEE step, 5-op carried chain (q0->rr->q->a->fma); cmp/sf/m off-chain.
//   q = RN(u/20) via Markstein; u' = fma(u-q, m, I), m = sp_prev?0:1
//   (m=1: RN(a+I) identical to add; m=0: reset path == I exactly)
#define LIF_CORE(U, SP, M, IIN)               \
    float q0 = (U) * cdiv;                    \
    float rr = fmaf(-20.0f, q0, (U));         \
    float q  = fmaf(rr, cdiv, q0);            \
    float a  = (U) - q;                       \
    (U) = fmaf(a, (M), (IIN));                \
    (SP) = ((U) >= 1.0f);

#define WARM_STEP(U, SP, M, IIN)              \
    {                                         \
        LIF_CORE(U, SP, M, IIN)               \
        (M) = (SP) ? 0.0f : 1.0f;             \
    }

#define FULL_STEP(U, SP, M, CNT, SEEN, AS, AF, IIN, SOUT) \
    {                                         \
        LIF_CORE(U, SP, M, IIN)               \
        float sf = (SP) ? 1.0f : 0.0f;        \
        (M) = 1.0f - sf;                      \
        (CNT) += sf;                          \
        (SEEN) = fmaxf((SEEN), sf);           \
        (AS) += (CNT);                        \
        (AF) += (SEEN);                       \
        (SOUT) = sf;                          \
    }

// Block = 128 threads: wave 0 computes 128 rows (2 chains/lane, interleaved
// for ILP), wave 1 stages global->LDS, double-buffered, raw s_barrier.
__global__ __launch_bounds__(128, 1) void lif_kernel(const float* __restrict__ I,
                                                     float* __restrict__ out,
                                                     float* __restrict__ Cacc,
                                                     float* __restrict__ tsAcc,
                                                     int* __restrict__ firstAcc) {
    __shared__ __align__(16) float lds[2][RPB * LSTRIDE];
    const int wid = threadIdx.x >> 6;
    const int lane = threadIdx.x & 63;
    const int seg = blockIdx.x >> 5;              // 16 segs
    const int rowBase = (blockIdx.x & 31) * RPB;  // 32 row-groups
    const int t0 = seg * SEGLEN;
    const int start = (t0 > WARM) ? (t0 - WARM) : 0;  // segs 0,1: exact from t=0
    const int warmSteps = t0 - start;                 // 0, 256, or 512
    const int nwarmCh = warmSteps / CHUNK;
    const int nch = nwarmCh + SEGLEN / CHUNK;

#define PROD_BAR() asm volatile("s_waitcnt lgkmcnt(0)\n\ts_barrier" ::: "memory")
#define COMP_BAR() asm volatile("s_barrier" ::: "memory")

    if (wid == 1) {
        // ---- producer wave: 128 rows x 32 steps per chunk ----
        const int srow = lane >> 3, scol = lane & 7;  // 8 rows/cluster, 8 f4 cols
        const float* gb = I + (size_t)(rowBase + srow) * L_DIM + start + scol * 4;
        {
            float* dst = &lds[0][0];
#pragma unroll
            for (int p = 0; p < 16; ++p) {
                const int r = p * 8 + srow;
                f4 v = *(const f4*)(gb + (size_t)(p * 8) * L_DIM);
                *(f4*)&dst[r * LSTRIDE + scol * 4] = v;
            }
        }
        PROD_BAR();
        for (int c = 0; c < nch; ++c) {
            if (c + 1 < nch) {
                const float* g = gb + (c + 1) * CHUNK;
                float* dst = &lds[(c + 1) & 1][0];
#pragma unroll
                for (int p = 0; p < 16; ++p) {
                    const int r = p * 8 + srow;
                    f4 v = *(const f4*)(g + (size_t)(p * 8) * L_DIM);
                    *(f4*)&dst[r * LSTRIDE + scol * 4] = v;
                }
            }
            PROD_BAR();
        }
    } else {
        // ---- compute wave: chains A (row lane) and B (row lane+64) ----
        const int rowA = rowBase + lane, rowB = rowA + 64;
        float uA = 0.f, cntA = 0.f, seenA = 0.f, asA = 0.f, afA = 0.f, mA = 1.f;
        float uB = 0.f, cntB = 0.f, seenB = 0.f, asB = 0.f, afB = 0.f, mB = 1.f;
        bool spA = false, spB = false;
        const float cdiv = 0.05f;  // RN(1/20)
        float* soA = out + (size_t)rowA * L_DIM + t0;
        float* soB = out + (size_t)rowB * L_DIM + t0;

        COMP_BAR();
        for (int c = 0; c < nch; ++c) {
            const float* bufA = &lds[c & 1][lane * LSTRIDE];
            const float* bufB = bufA + 64 * LSTRIDE;
            f4 a0 = *(const f4*)(bufA + 0),  a1 = *(const f4*)(bufA + 4);
            f4 a2 = *(const f4*)(bufA + 8),  a3 = *(const f4*)(bufA + 12);
            f4 a4 = *(const f4*)(bufA + 16), a5 = *(const f4*)(bufA + 20);
            f4 a6 = *(const f4*)(bufA + 24), a7 = *(const f4*)(bufA + 28);
            f4 b0 = *(const f4*)(bufB + 0),  b1 = *(const f4*)(bufB + 4);
            f4 b2 = *(const f4*)(bufB + 8),  b3 = *(const f4*)(bufB + 12);
            f4 b4 = *(const f4*)(bufB + 16), b5 = *(const f4*)(bufB + 20);
            f4 b6 = *(const f4*)(bufB + 24), b7 = *(const f4*)(bufB + 28);
            asm volatile("" : "+v"(a0), "+v"(a1), "+v"(a2), "+v"(a3),
                             "+v"(a4), "+v"(a5), "+v"(a6), "+v"(a7),
                             "+v"(b0), "+v"(b1), "+v"(b2), "+v"(b3),
                             "+v"(b4), "+v"(b5), "+v"(b6), "+v"(b7));

            if (c < nwarmCh) {
#define WQ(RA, RB)                                                     \
                { WARM_STEP(uA, spA, mA, RA.x) WARM_STEP(uB, spB, mB, RB.x)  \
                  WARM_STEP(uA, spA, mA, RA.y) WARM_STEP(uB, spB, mB, RB.y)  \
                  WARM_STEP(uA, spA, mA, RA.z) WARM_STEP(uB, spB, mB, RB.z)  \
                  WARM_STEP(uA, spA, mA, RA.w) WARM_STEP(uB, spB, mB, RB.w) }
                WQ(a0, b0) WQ(a1, b1) WQ(a2, b2) WQ(a3, b3)
                WQ(a4, b4) WQ(a5, b5) WQ(a6, b6) WQ(a7, b7)
#undef WQ
            } else {
                float* sdA = soA + (c - nwarmCh) * CHUNK;
                float* sdB = soB + (c - nwarmCh) * CHUNK;
#define FS_A(IIN, SOUT) FULL_STEP(uA, spA, mA, cntA, seenA, asA, afA, IIN, SOUT)
#define FS_B(IIN, SOUT) FULL_STEP(uB, spB, mB, cntB, seenB, asB, afB, IIN, SOUT)
#define FQ(RA, RB, J)                                                  \
                {                                                      \
                    f4 svA, svB;                                       \
                    FS_A(RA.x, svA.x) FS_B(RB.x, svB.x)                \
                    FS_A(RA.y, svA.y) FS_B(RB.y, svB.y)                \
                    FS_A(RA.z, svA.z) FS_B(RB.z, svB.z)                \
                    FS_A(RA.w, svA.w) FS_B(RB.w, svB.w)                \
                    *(f4*)(sdA + 4 * (J)) = svA;                       \
                    *(f4*)(sdB + 4 * (J)) = svB;                       \
                }
                FQ(a0, b0, 0) FQ(a1, b1, 1) FQ(a2, b2, 2) FQ(a3, b3, 3)
                FQ(a4, b4, 4) FQ(a5, b5, 5) FQ(a6, b6, 6) FQ(a7, b7, 7)
#undef FQ
#undef FS_A
#undef FS_B
            }
            COMP_BAR();
        }

        // partials: exact integers < 2^24 -> float atomics exact
        if (cntA > 0.f) atomicMin(&firstAcc[rowA], t0 + (int)((float)SEGLEN - afA));
        atomicAdd(&Cacc[rowA], cntA);
        atomicAdd(&tsAcc[rowA], fmaf((float)(t0 + SEGLEN), cntA, -asA));
        if (cntB > 0.f) atomicMin(&firstAcc[rowB], t0 + (int)((float)SEGLEN - afB));
        atomicAdd(&Cacc[rowB], cntB);
        atomicAdd(&tsAcc[rowB], fmaf((float)(t0 + SEGLEN), cntB, -asB));
    }
#undef PROD_BAR
#undef COMP_BAR
}

__global__ __launch_bounds__(256) void fin_kernel(const float* __restrict__ Cacc,
                                                  const float* __restrict__ tsAcc,
                                                  const int* __restrict__ firstAcc,
                                                  float* __restrict__ out) {
    int r = blockIdx.x * 256 + threadIdx.x;
    if (r < B_DIM) {
        out[(size_t)B_DIM * L_DIM + r] = (float)firstAcc[r];
        out[(size_t)B_DIM * L_DIM + B_DIM + r] = tsAcc[r] / (Cacc[r] + 1e-6f);
    }
}

extern "C" void kernel_launch(void* const* d_in, const int* in_sizes, int n_in,
                              void* d_out, int out_size, void* d_ws, size_t ws_size,
                              hipStream_t stream) {
    const float* I = (const float*)d_in[0];
    float* out = (float*)d_out;
    float* wsf = (float*)d_ws;
    int* wsi = (int*)((float*)d_ws + 2 * B_DIM);
    (void)in_sizes; (void)n_in; (void)out_size; (void)ws_size;

    init_kernel<<<(2 * B_DIM + 255) / 256, 256, 0, stream>>>(wsf, wsi);
    lif_kernel<<<(B_DIM / RPB) * NSEG, 128, 0, stream>>>(I, out, wsf, wsf + B_DIM, wsi);
    fin_kernel<<<(B_DIM + 255) / 256, 256, 0, stream>>>(wsf, wsf + B_DIM, wsi, out);
}

// Round 8
// 134.484 us; speedup vs baseline: 1.0683x; 1.0683x over previous
//
#include <hip/hip_runtime.h>

#define B_DIM 4096
#define L_DIM 4096
#define SEGLEN 512
#define NSEG (L_DIM / SEGLEN)   // 8
#define WARM 512                // warm-up for seg>0 (proven absmax 0)
#define CHUNK 64                // time steps per LDS chunk
#define LSTRIDE 64              // NO pad: global_load_lds needs lane-linear dest
#define ROWS 64                 // rows per block (one per compute lane)

typedef float f4 __attribute__((ext_vector_type(4)));

// ws: float C_acc[4096], float ts_acc[4096], int first_acc[4096]
__global__ __launch_bounds__(256) void init_kernel(float* wsf, int* wsi) {
    int i = blockIdx.x * 256 + threadIdx.x;
    if (i < 2 * B_DIM) wsf[i] = 0.f;
    if (i < B_DIM) wsi[i] = L_DIM;
}

// Exact IEEE step (proven absmax 0): q = RN(u/20) via Markstein, compare off
// the dependent chain: u' = sp_prev ? I' : ((u - q) + I')  [reset == I' exactly]
#define LIF_CORE(IIN)                         \
    float q0 = u * cdiv;                      \
    float rr = fmaf(-20.0f, q0, u);           \
    float q  = fmaf(rr, cdiv, q0);            \
    float a  = u - q;                         \
    float b  = a + (IIN);                     \
    u = sp ? (IIN) : b;                       \
    sp = (u >= 1.0f);

#define WARM_STEP(IIN) { LIF_CORE(IIN) }

#define FULL_STEP(IIN, SOUT)                  \
    {                                         \
        LIF_CORE(IIN)                         \
        float sf = sp ? 1.0f : 0.0f;          \
        cnt += sf;                            \
        seen = fmaxf(seen, sf);               \
        accS += cnt;                          \
        accF += seen;                         \
        (SOUT) = sf;                          \
    }

// async global -> LDS, 16B per lane (no VGPR round trip)
__device__ __forceinline__ void dma16(const float* g, float* l) {
    __builtin_amdgcn_global_load_lds(
        (const __attribute__((address_space(1))) unsigned int*)g,
        (__attribute__((address_space(3))) unsigned int*)l, 16, 0, 0);
}

// Block = 128 threads: wave 0 computes 64 rows (row-per-lane, one segment),
// wave 1 streams global->LDS via global_load_lds DMA (16 back-to-back issues,
// one vmcnt(0) drain per chunk). Double-buffered, raw s_barrier.
__global__ __launch_bounds__(128, 1) void lif_kernel(const float* __restrict__ I,
                                                     float* __restrict__ out,
                                                     float* __restrict__ Cacc,
                                                     float* __restrict__ tsAcc,
                                                     int* __restrict__ firstAcc) {
    __shared__ __align__(16) float lds[2][ROWS * LSTRIDE];
    const int wid = threadIdx.x >> 6;
    const int lane = threadIdx.x & 63;
    const int seg = blockIdx.x >> 6;
    const int rowBase = (blockIdx.x & 63) * ROWS;
    const int t0 = seg * SEGLEN;
    const int start = (seg == 0) ? 0 : (t0 - WARM);
    const int nwarmCh = (seg == 0) ? 0 : (WARM / CHUNK);
    const int nch = nwarmCh + SEGLEN / CHUNK;

#define PROD_BAR() asm volatile("s_waitcnt vmcnt(0)\n\ts_barrier" ::: "memory")
#define COMP_BAR() asm volatile("s_barrier" ::: "memory")

    if (wid == 1) {
        // ---- producer wave: DMA chunk into LDS, wave-uniform base + lane*16.
        // instr p covers rows 4p..4p+3; lane -> (row 4p+(lane>>4), f4col lane&15)
        const int srow = lane >> 4, scol = lane & 15;
        const float* gb = I + (size_t)(rowBase + srow) * L_DIM + start + scol * 4;
        {
            float* dst = &lds[0][0] + lane * 4;  // lane-linear within instr
#pragma unroll
            for (int p = 0; p < 16; ++p)
                dma16(gb + (size_t)(4 * p) * L_DIM, dst + p * 256);
        }
        PROD_BAR();
        for (int c = 0; c < nch; ++c) {
            if (c + 1 < nch) {
                const float* g = gb + (c + 1) * CHUNK;
                float* dst = &lds[(c + 1) & 1][0] + lane * 4;
#pragma unroll
                for (int p = 0; p < 16; ++p)
                    dma16(g + (size_t)(4 * p) * L_DIM, dst + p * 256);
            }
            PROD_BAR();
        }
    } else {
        // ---- compute wave: one row per lane ----
        const int row = rowBase + lane;
        float u = 0.f, cnt = 0.f, seen = 0.f, accS = 0.f, accF = 0.f;
        bool sp = false;
        const float cdiv = 0.05f;  // RN(1/20)
        float* so = out + (size_t)row * L_DIM + t0;

        COMP_BAR();  // chunk 0 staged
        for (int c = 0; c < nch; ++c) {
            const float* buf = &lds[c & 1][lane * LSTRIDE];
            f4 r0 = *(const f4*)(buf + 0),  r1 = *(const f4*)(buf + 4);
            f4 r2 = *(const f4*)(buf + 8),  r3 = *(const f4*)(buf + 12);
            f4 r4 = *(const f4*)(buf + 16), r5 = *(const f4*)(buf + 20);
            f4 r6 = *(const f4*)(buf + 24), r7 = *(const f4*)(buf + 28);
            f4 r8 = *(const f4*)(buf + 32), r9 = *(const f4*)(buf + 36);
            f4 r10 = *(const f4*)(buf + 40), r11 = *(const f4*)(buf + 44);
            f4 r12 = *(const f4*)(buf + 48), r13 = *(const f4*)(buf + 52);
            f4 r14 = *(const f4*)(buf + 56), r15 = *(const f4*)(buf + 60);
            asm volatile("" : "+v"(r0), "+v"(r1), "+v"(r2), "+v"(r3),
                             "+v"(r4), "+v"(r5), "+v"(r6), "+v"(r7),
                             "+v"(r8), "+v"(r9), "+v"(r10), "+v"(r11),
                             "+v"(r12), "+v"(r13), "+v"(r14), "+v"(r15));

            if (c < nwarmCh) {
#define WQ(RK) { WARM_STEP(RK.x) WARM_STEP(RK.y) WARM_STEP(RK.z) WARM_STEP(RK.w) }
                WQ(r0) WQ(r1) WQ(r2) WQ(r3) WQ(r4) WQ(r5) WQ(r6) WQ(r7)
                WQ(r8) WQ(r9) WQ(r10) WQ(r11) WQ(r12) WQ(r13) WQ(r14) WQ(r15)
#undef WQ
            } else {
                float* sd = so + (c - nwarmCh) * CHUNK;
#define FQ(RK, QI)                                                    \
                {                                                     \
                    f4 sv;                                            \
                    FULL_STEP(RK.x, sv.x) FULL_STEP(RK.y, sv.y)       \
                    FULL_STEP(RK.z, sv.z) FULL_STEP(RK.w, sv.w)       \
                    *(f4*)(sd + 4 * (QI)) = sv;                       \
                }
                FQ(r0, 0) FQ(r1, 1) FQ(r2, 2) FQ(r3, 3)
                FQ(r4, 4) FQ(r5, 5) FQ(r6, 6) FQ(r7, 7)
                FQ(r8, 8) FQ(r9, 9) FQ(r10, 10) FQ(r11, 11)
                FQ(r12, 12) FQ(r13, 13) FQ(r14, 14) FQ(r15, 15)
#undef FQ
            }
            COMP_BAR();
        }

        // per-segment partials (exact integers < 2^24 -> float atomics exact)
        if (cnt > 0.f) {
            const int firstLocal = (int)((float)SEGLEN - accF);
            atomicMin(&firstAcc[row], t0 + firstLocal);
        }
        atomicAdd(&Cacc[row], cnt);
        atomicAdd(&tsAcc[row], fmaf((float)(t0 + SEGLEN), cnt, -accS));
    }
#undef PROD_BAR
#undef COMP_BAR
}

__global__ __launch_bounds__(256) void fin_kernel(const float* __restrict__ Cacc,
                                                  const float* __restrict__ tsAcc,
                                                  const int* __restrict__ firstAcc,
                                                  float* __restrict__ out) {
    int r = blockIdx.x * 256 + threadIdx.x;
    if (r < B_DIM) {
        out[(size_t)B_DIM * L_DIM + r] = (float)firstAcc[r];
        out[(size_t)B_DIM * L_DIM + B_DIM + r] = tsAcc[r] / (Cacc[r] + 1e-6f);
    }
}

extern "C" void kernel_launch(void* const* d_in, const int* in_sizes, int n_in,
                              void* d_out, int out_size, void* d_ws, size_t ws_size,
                              hipStream_t stream) {
    const float* I = (const float*)d_in[0];
    float* out = (float*)d_out;
    float* wsf = (float*)d_ws;
    int* wsi = (int*)((float*)d_ws + 2 * B_DIM);
    (void)in_sizes; (void)n_in; (void)out_size; (void)ws_size;

    init_kernel<<<(2 * B_DIM + 255) / 256, 256, 0, stream>>>(wsf, wsi);
    lif_kernel<<<NSEG * 64, 128, 0, stream>>>(I, out, wsf, wsf + B_DIM, wsi);
    fin_kernel<<<(B_DIM + 255) / 256, 256, 0, stream>>>(wsf, wsf + B_DIM, wsi, out);
}